// Round 5
// baseline (266.412 us; speedup 1.0000x reference)
//
#include <hip/hip_runtime.h>
#include <hip/hip_bf16.h>

// Modulated conv2d (StyleGAN2) on MI355X.
// out[b,o] = rsig[b,o] * conv(s[b,:]*x[b,:], W*SCALE)   (shared weights)
// R5: LDS-traffic reduction. (1) tap-superset B staging: per ci-group g
// stage the 10x34-row x 64-ci xpad slice ONCE (48KB serves all 9 taps;
// B writes 288KB->48KB/group). (2) K-split waves 2Mx2Nx2K, per-wave 64x128
// (reads 128->96KB/tile), accumulators merged via LDS at the end.
// One s_barrier per tap, counted vmcnt (B staged 8 taps ahead, A 2 ahead).

typedef __attribute__((ext_vector_type(4))) float f32x4;
typedef __attribute__((ext_vector_type(8))) short bf16x8;

#define NB    16
#define CIN   512
#define COUT  512
#define KTOT  4608
#define NPIX  (NB * 32 * 32)

#define WAITV8() asm volatile("s_waitcnt vmcnt(8)" ::: "memory")
#define WAITV2() asm volatile("s_waitcnt vmcnt(2)" ::: "memory")
#define WAITV0() asm volatile("s_waitcnt vmcnt(0)" ::: "memory")
#define FENCE()  asm volatile("" ::: "memory")
#define BAR()    { FENCE(); __builtin_amdgcn_s_barrier(); FENCE(); }

__device__ __forceinline__ void gload_lds16(const void* g, void* l) {
  __builtin_amdgcn_global_load_lds(
      (__attribute__((address_space(1))) void*)(g),
      (__attribute__((address_space(3))) void*)(l), 16, 0, 0);
}

// ---- kernel 1: pack weights as wB2[o][g=ci>>6][tap][ci&63] bf16 + wsq ----
__global__ __launch_bounds__(256) void pack_w_kernel(
    const float* __restrict__ w, __hip_bfloat16* __restrict__ wB2,
    float* __restrict__ wsq) {
  const int idx = blockIdx.x * 256 + threadIdx.x;   // = o*512 + ci
  const int o = idx >> 9, ci = idx & 511;
  const float* wp = w + (size_t)idx * 9;
  const float WSCALE = 0.014731391274719739f;       // 1/sqrt(512*9)
  float sum = 0.f;
#pragma unroll
  for (int t = 0; t < 9; ++t) {
    float v = wp[t] * WSCALE;
    sum += v * v;
    wB2[(size_t)o * KTOT + (ci >> 6) * 576 + t * 64 + (ci & 63)] =
        __float2bfloat16(v);
  }
  wsq[idx] = sum;
}

// ---- kernel 2: rsig[b][o] ----
__global__ __launch_bounds__(256) void calc_rsig_kernel(
    const float* __restrict__ s, const float* __restrict__ wsq,
    float* __restrict__ rsig) {
  const int wid = blockIdx.x * 4 + (threadIdx.x >> 6);
  const int lane = threadIdx.x & 63;
  const int b = wid >> 9, o = wid & 511;
  const float* sp = s + b * 512;
  const float* wp = wsq + o * 512;
  float sum = 0.f;
#pragma unroll
  for (int i = 0; i < 8; ++i) {
    float sv = sp[lane + i * 64];
    sum += sv * sv * wp[lane + i * 64];
  }
#pragma unroll
  for (int off = 32; off > 0; off >>= 1) sum += __shfl_down(sum, off, 64);
  if (lane == 0) rsig[wid] = 1.0f / sqrtf(sum + 1e-8f);
}

// ---- kernel 3: modulate + NCHW -> padded channels-last bf16 ----
__global__ __launch_bounds__(256) void modulate_kernel(
    const float* __restrict__ x, const float* __restrict__ s,
    __hip_bfloat16* __restrict__ xpad) {
  const int by = blockIdx.x;            // b*32 + y
  const int b = by >> 5, y = by & 31;
  __shared__ __attribute__((aligned(16))) __hip_bfloat16 tile[32][72];
  const int tid = threadIdx.x;
  const int xc = tid & 31;
  const int cr0 = tid >> 5;
  const float* xrow = x + ((size_t)b * 512 * 32 + y) * 32;
  const float* sb = s + b * 512;
  __hip_bfloat16* orow = xpad + (size_t)((b * 34 + y + 1) * 34) * 512;

  for (int ci0 = 0; ci0 < 512; ci0 += 64) {
#pragma unroll
    for (int r = 0; r < 8; ++r) {
      const int cir = r * 8 + cr0;
      const int ci = ci0 + cir;
      float v = xrow[(size_t)ci * 1024 + xc] * sb[ci];
      tile[xc][cir] = __float2bfloat16(v);
    }
    __syncthreads();
    const int xcw = tid >> 3, vec = tid & 7;
    bf16x8 v = *(const bf16x8*)&tile[xcw][vec * 8];
    *(bf16x8*)(orow + (size_t)(xcw + 1) * 512 + ci0 + vec * 8) = v;
    __syncthreads();
  }
}

// ---- kernel 4: implicit-GEMM conv, superset-B + K-split waves ----
// LDS bytes: A bufs: 3 x 16KB at 0; B bufs: 2 x 48KB at 49152.
// A buf = [128 o-rows][64 ci'] rows of 128B; B buf = [340 pixel-rows][64 ci']
// rows of 128B (10x34 xpad slice; rows beyond 339 are pad from clamped loads).
// XOR swizzle byte ^= ((row&7)<<4) on staging source slot + ds_read (rule 21).
__global__ __launch_bounds__(512, 2) void conv_gemm_kernel(
    const __hip_bfloat16* __restrict__ wB2,   // [512][8][9][64]
    const __hip_bfloat16* __restrict__ xpad,  // [16][34][34][512]
    const float* __restrict__ rsig,           // [16][512]
    float* __restrict__ out) {                // [16][512][32][32]
  extern __shared__ __attribute__((aligned(16))) char ldsc[];

  const int tid = threadIdx.x;
  const int wv = tid >> 6, lane = tid & 63;
  const int l15 = lane & 15;
  const int bo0 = blockIdx.y << 7;        // cout block (128)
  const int bp0 = blockIdx.x << 8;        // pixel block (256)
  const int bimg = blockIdx.x >> 2;       // image
  const int y0 = (blockIdx.x & 3) << 3;   // first output row (8 rows/block)
  const int wr = wv >> 2, wc = (wv >> 1) & 1, wk = wv & 1;
  const int kb = (wk << 6) | ((lane >> 4) << 4);  // k-byte within 128B row

  // rsig preload + pin (keeps vmcnt accounting in the loop exact).
  f32x4 rs[4];
#pragma unroll
  for (int mi = 0; mi < 4; ++mi) {
    rs[mi] = *(const f32x4*)(rsig + (bimg << 9) + bo0 + (wr << 6) + (mi << 4) +
                             ((lane >> 4) << 2));
    asm volatile("" ::"v"(rs[mi]));   // force materialization before staging
  }

  // A staging source offsets (elements); add g*576 + tap*64 per tile.
  int gA[2];
#pragma unroll
  for (int r = 0; r < 2; ++r) {
    const int c = r * 512 + tid, row = c >> 3, sc = (c & 7) ^ (row & 7);
    gA[r] = (bo0 + row) * KTOT + sc * 8;
  }
  // B superset staging source offsets (elements); add g*64 per group.
  int gB[6];
#pragma unroll
  for (int r = 0; r < 6; ++r) {
    const int u = r * 512 + tid;
    int R = u >> 3; if (R > 339) R = 339;          // pad units -> clamp
    const int sc = (u & 7) ^ (R & 7);
    const int yl = R / 34, xl = R - yl * 34;
    gB[r] = ((bimg * 34 + y0 + yl) * 34 + xl) * 512 + sc * 8;
  }
  // B-row base per n-frag: R = Rb[ni] + ty*34 + tx
  int Rb[8];
#pragma unroll
  for (int ni = 0; ni < 8; ++ni) {
    const int p = (wc << 7) + (ni << 4) + l15;
    Rb[ni] = (p >> 5) * 34 + (p & 31);
  }

  auto stageA = [&](int bufi, int koff) {   // koff = g*576 + tap*64 (elements)
    char* dst = ldsc + bufi * 16384;
#pragma unroll
    for (int r = 0; r < 2; ++r)
      gload_lds16(wB2 + (size_t)(gA[r] + koff), dst + (r * 512 + tid) * 16);
  };
  auto stageB = [&](int gi) {               // 6 rounds -> 48KB (incl. pad)
    char* dst = ldsc + 49152 + (gi & 1) * 49152;
#pragma unroll
    for (int r = 0; r < 6; ++r)
      gload_lds16(xpad + (size_t)(gB[r] + gi * 64), dst + (r * 512 + tid) * 16);
  };

  f32x4 acc[4][8];
#pragma unroll
  for (int mi = 0; mi < 4; ++mi)
#pragma unroll
    for (int ni = 0; ni < 8; ++ni) acc[mi][ni] = f32x4{0.f, 0.f, 0.f, 0.f};

  // Prologue: B(0) 6 | A(kt=0) 2 | A(kt=1) 2 -> vmcnt(2) leaves A(1) in flight.
  stageB(0);
  stageA(0, 0);
  stageA(1, 64);
  WAITV2();
  BAR();

#pragma unroll 1
  for (int g = 0; g < 8; ++g) {
    const char* bufB = ldsc + 49152 + (g & 1) * 49152;
#pragma unroll
    for (int tap = 0; tap < 9; ++tap) {
      // ---- staging for the future ----
      if (tap == 0) { if (g < 7) stageB(g + 1); }
      {  // stage A(kt+2) if it exists; buf (tap+2)%3, koff compile-time split
        const int t2 = (tap < 7) ? tap + 2 : tap - 7;
        const bool have = (tap <= 6) || (g < 7);
        if (have) {
          const int g2 = (tap < 7) ? g : g + 1;
          stageA((tap + 2) % 3, g2 * 576 + t2 * 64);
        }
      }
      // ---- fragment reads (tile kt) ----
      const char* bufA = ldsc + (tap % 3) * 16384;
      const int TY = tap / 3, TX = tap % 3;
      bf16x8 av[4], bv[8];
#pragma unroll
      for (int mi = 0; mi < 4; ++mi) {
        const int row = (wr << 6) + (mi << 4) + l15;
        av[mi] = *(const bf16x8*)(bufA + row * 128 + (kb ^ ((row & 7) << 4)));
      }
#pragma unroll
      for (int ni = 0; ni < 8; ++ni) {
        const int R = Rb[ni] + TY * 34 + TX;
        bv[ni] = *(const bf16x8*)(bufB + R * 128 + (kb ^ ((R & 7) << 4)));
      }
      // ---- MFMA: 4x8, one K32 step (this wave's ci-half) ----
      __builtin_amdgcn_s_setprio(1);
#pragma unroll
      for (int mi = 0; mi < 4; ++mi)
#pragma unroll
        for (int ni = 0; ni < 8; ++ni)
          acc[mi][ni] = __builtin_amdgcn_mfma_f32_16x16x32_bf16(
              av[mi], bv[ni], acc[mi][ni], 0, 0, 0);
      __builtin_amdgcn_s_setprio(0);
      // ---- boundary wait: guarantee A(kt+1) [+B(g') at group edges] ----
      if (tap == 0)      { if (g < 7) { WAITV8(); } else { WAITV2(); } }
      else if (tap >= 7) { if (g < 7) { WAITV2(); } else { WAITV0(); } }
      else               { WAITV2(); }
      BAR();
    }
  }

  // ---- K-split merge: wk=1 waves park acc in LDS, wk=0 add + epilogue ----
  const int slot = ((wr << 1) | wc) << 15;   // 32KB per (wr,wc) pair
  if (wk) {
#pragma unroll
    for (int mi = 0; mi < 4; ++mi)
#pragma unroll
      for (int ni = 0; ni < 8; ++ni)
        *(f32x4*)(ldsc + slot + (((mi << 3) | ni) << 10) + (lane << 4)) =
            acc[mi][ni];
  }
  __syncthreads();
  if (!wk) {
#pragma unroll
    for (int mi = 0; mi < 4; ++mi) {
      const int o = bo0 + (wr << 6) + (mi << 4) + ((lane >> 4) << 2);
#pragma unroll
      for (int ni = 0; ni < 8; ++ni) {
        const f32x4 o4 =
            *(const f32x4*)(ldsc + slot + (((mi << 3) | ni) << 10) + (lane << 4));
        const f32x4 a = acc[mi][ni] + o4;
        const int p = bp0 + (wc << 7) + (ni << 4) + l15;
        const int prem = p & 1023;
#pragma unroll
        for (int r = 0; r < 4; ++r)
          out[((size_t)(bimg << 9) + o + r) * 1024 + prem] = a[r] * rs[mi][r];
      }
    }
  }
}

extern "C" void kernel_launch(void* const* d_in, const int* in_sizes, int n_in,
                              void* d_out, int out_size, void* d_ws,
                              size_t ws_size, hipStream_t stream) {
  const float* x = (const float*)d_in[0];   // [16,512,32,32]
  const float* s = (const float*)d_in[1];   // [16,512]
  const float* w = (const float*)d_in[2];   // [512,512,3,3]
  float* out = (float*)d_out;               // [16,512,32,32] f32

  char* ws = (char*)d_ws;
  const size_t xpad_bytes = (size_t)NB * 34 * 34 * 512 * 2;  // 18,939,904
  const size_t wB_bytes = (size_t)COUT * KTOT * 2;           //  4,718,592
  const size_t wsq_bytes = (size_t)COUT * CIN * 4;           //  1,048,576
  __hip_bfloat16* xpad = (__hip_bfloat16*)ws;
  __hip_bfloat16* wB2 = (__hip_bfloat16*)(ws + xpad_bytes);
  float* wsq = (float*)(ws + xpad_bytes + wB_bytes);
  float* rsig = (float*)(ws + xpad_bytes + wB_bytes + wsq_bytes);

  const int lds_bytes = 147456;   // 48KB A (3 bufs) + 96KB B (2 bufs)
  hipFuncSetAttribute((const void*)conv_gemm_kernel,
                      hipFuncAttributeMaxDynamicSharedMemorySize, lds_bytes);

  hipMemsetAsync(xpad, 0, xpad_bytes, stream);  // zero halo (capturable)
  pack_w_kernel<<<(COUT * CIN) / 256, 256, 0, stream>>>(w, wB2, wsq);
  modulate_kernel<<<NB * 32, 256, 0, stream>>>(x, s, xpad);
  calc_rsig_kernel<<<(NB * COUT) / 4, 256, 0, stream>>>(s, wsq, rsig);
  conv_gemm_kernel<<<dim3(NPIX / 256, COUT / 128), 512, lds_bytes, stream>>>(
      wB2, xpad, rsig, out);
}

// Round 6
// 105.595 us; speedup vs baseline: 2.5230x; 2.5230x over previous
//
#include <hip/hip_runtime.h>
#include <hip/hip_bf16.h>

// Modulated conv2d (StyleGAN2) on MI355X.
// out[b,o] = rsig[b,o] * conv(s[b,:]*x[b,:], W*SCALE)   (shared weights)
// rsig[b,o] = 1/sqrt(sum_i s[b,i]^2 * wsq[o,i] + 1e-8)
// Conv as implicit GEMM: D[o][p] = sum_k Wb[o][k] * Xcl[p][k].
//
// R6: K-split x2. Per-CU-area argument: grid>=512 blocks caps per-wave tile
// at 64x64 (LDS:MFMA ratio 0.64). Splitting K (grid 64x4x2=512 blocks of
// 128x256 x K2304) doubles per-CU area -> per-wave 64x128 (mu4 x nu8, ratio
// 0.90) and HALVES total barrier/vmcnt-drain count (512x36 vs 512x72 tiles).
// Structure = R1's proven simple 2-barrier __syncthreads loop, 2 blocks/CU.
// z=0 writes rsig-scaled f32 to out; z=1 writes rsig-scaled bf16 partial to
// ws; merge kernel adds them (out += p1).

typedef __attribute__((ext_vector_type(4))) float f32x4;
typedef __attribute__((ext_vector_type(8))) short bf16x8;

#define NB    16
#define CIN   512
#define COUT  512
#define KTOT  4608           // CIN * 9
#define NPIX  (NB * 32 * 32) // 16384

__device__ __forceinline__ void gload_lds16(const void* g, void* l) {
  __builtin_amdgcn_global_load_lds(
      (__attribute__((address_space(1))) void*)(g),
      (__attribute__((address_space(3))) void*)(l), 16, 0, 0);
}

// ---- kernel 1: pack weights (bf16, [o][tap*512+ci]) + wsq ----
__global__ __launch_bounds__(256) void pack_w_kernel(
    const float* __restrict__ w, __hip_bfloat16* __restrict__ wB,
    float* __restrict__ wsq) {
  const int idx = blockIdx.x * 256 + threadIdx.x;   // = o*512 + ci
  const int o = idx >> 9, ci = idx & 511;
  const float* wp = w + (size_t)idx * 9;
  const float WSCALE = 0.014731391274719739f;       // 1/sqrt(512*9)
  float sum = 0.f;
#pragma unroll
  for (int t = 0; t < 9; ++t) {
    float v = wp[t] * WSCALE;
    sum += v * v;
    wB[(size_t)o * KTOT + t * 512 + ci] = __float2bfloat16(v);
  }
  wsq[idx] = sum;
}

// ---- kernel 2: rsig[b][o], one wave per (b,o) ----
__global__ __launch_bounds__(256) void calc_rsig_kernel(
    const float* __restrict__ s, const float* __restrict__ wsq,
    float* __restrict__ rsig) {
  const int wid = blockIdx.x * 4 + (threadIdx.x >> 6); // b*512 + o
  const int lane = threadIdx.x & 63;
  const int b = wid >> 9, o = wid & 511;
  const float* sp = s + b * 512;
  const float* wp = wsq + o * 512;
  float sum = 0.f;
#pragma unroll
  for (int i = 0; i < 8; ++i) {
    float sv = sp[lane + i * 64];
    sum += sv * sv * wp[lane + i * 64];
  }
#pragma unroll
  for (int off = 32; off > 0; off >>= 1) sum += __shfl_down(sum, off, 64);
  if (lane == 0) rsig[wid] = 1.0f / sqrtf(sum + 1e-8f);
}

// ---- kernel 3: modulate + NCHW -> padded channels-last bf16 ----
__global__ __launch_bounds__(256) void modulate_kernel(
    const float* __restrict__ x, const float* __restrict__ s,
    __hip_bfloat16* __restrict__ xpad) {
  const int by = blockIdx.x;            // b*32 + y
  const int b = by >> 5, y = by & 31;
  __shared__ __attribute__((aligned(16))) __hip_bfloat16 tile[32][72];
  const int tid = threadIdx.x;
  const int xc = tid & 31;
  const int cr0 = tid >> 5;
  const float* xrow = x + ((size_t)b * 512 * 32 + y) * 32;
  const float* sb = s + b * 512;
  __hip_bfloat16* orow = xpad + (size_t)((b * 34 + y + 1) * 34) * 512;

  for (int ci0 = 0; ci0 < 512; ci0 += 64) {
#pragma unroll
    for (int r = 0; r < 8; ++r) {
      const int cir = r * 8 + cr0;
      const int ci = ci0 + cir;
      float v = xrow[(size_t)ci * 1024 + xc] * sb[ci];
      tile[xc][cir] = __float2bfloat16(v);
    }
    __syncthreads();
    const int xcw = tid >> 3, vec = tid & 7;
    bf16x8 v = *(const bf16x8*)&tile[xcw][vec * 8];
    *(bf16x8*)(orow + (size_t)(xcw + 1) * 512 + ci0 + vec * 8) = v;
    __syncthreads();
  }
}

// ---- kernel 4: implicit-GEMM conv, K-split, per-wave 64x128 ----
// Block: 128 cout x 256 pix x K2304 (36 K64-tiles). 256 thr, 4 waves 2Mx2N,
// per-wave 64x128 (acc 4x8). LDS: A[128][64] 16KB + B[256][64] 32KB, single-
// buffered, row-major 128B rows, XOR swizzle byte^=((row&7)<<4) on staging
// source chunk + ds_read (rule 21; 0 conflicts measured R1-R4).
__global__ __launch_bounds__(256, 2) void conv_gemm_kernel(
    const __hip_bfloat16* __restrict__ wB,    // [512][4608]
    const __hip_bfloat16* __restrict__ xpad,  // [16][34][34][512]
    const float* __restrict__ rsig,           // [16][512]
    float* __restrict__ out,                  // z=0: [16][512][32][32] f32
    __hip_bfloat16* __restrict__ p1) {        // z=1 partial (bf16)
  __shared__ __attribute__((aligned(16))) __hip_bfloat16 ldsA[128 * 64];
  __shared__ __attribute__((aligned(16))) __hip_bfloat16 ldsB[256 * 64];

  const int tid = threadIdx.x;
  const int wv = tid >> 6, lane = tid & 63, l15 = lane & 15;
  const int bo0 = blockIdx.y << 7;   // cout block (128)
  const int bp0 = blockIdx.x << 8;   // pixel block (256; 256 | 1024 per image)
  const int z = blockIdx.z;          // K-half
  const int bimg = blockIdx.x >> 2;
  const int wr = wv >> 1, wc = wv & 1;

  // Staging source offsets (pre-swizzled chunk within row; rule 21).
  int gA[4];   // + ktg*64 per tile
#pragma unroll
  for (int r = 0; r < 4; ++r) {
    const int c = r * 256 + tid, row = c >> 3, sc = (c & 7) ^ (row & 7);
    gA[r] = (bo0 + row) * KTOT + sc * 8;
  }
  int gB[8];   // + tapoff*512 + ci0 per tile
#pragma unroll
  for (int r = 0; r < 8; ++r) {
    const int c = r * 256 + tid, row = c >> 3, sc = (c & 7) ^ (row & 7);
    const int p = bp0 + row, b = p >> 10, rem = p & 1023, y = rem >> 5,
              xx = rem & 31;
    gB[r] = ((b * 34 + y) * 34 + xx) * 512 + sc * 8;
  }

  f32x4 acc[4][8];
#pragma unroll
  for (int mi = 0; mi < 4; ++mi)
#pragma unroll
    for (int ni = 0; ni < 8; ++ni) acc[mi][ni] = f32x4{0.f, 0.f, 0.f, 0.f};

  const int kb0 = (lane >> 4) << 4;   // byte base of this lane's k-slot

#pragma unroll 1
  for (int kt = 0; kt < 36; ++kt) {
    const int ktg = z * 36 + kt;
    const int tap = ktg >> 3;
    const int xoff = (tap + 31 * (tap / 3)) * 512 + ((ktg & 7) << 6);
    // ---- stage tile (12 x 16B per thread) ----
#pragma unroll
    for (int r = 0; r < 4; ++r)
      gload_lds16(wB + (size_t)(gA[r] + (ktg << 6)),
                  (char*)ldsA + (r * 256 + tid) * 16);
#pragma unroll
    for (int r = 0; r < 8; ++r)
      gload_lds16(xpad + (size_t)(gB[r] + xoff),
                  (char*)ldsB + (r * 256 + tid) * 16);
    __syncthreads();   // drains vmcnt -> staged data visible

    // ---- A frags (both k-halves), B frags per k-half ----
    bf16x8 af[4][2];
#pragma unroll
    for (int mi = 0; mi < 4; ++mi) {
      const int row = (wr << 6) + (mi << 4) + l15;
      const int swz = (row & 7) << 4;
      af[mi][0] = *(const bf16x8*)((const char*)ldsA + row * 128 + (kb0 ^ swz));
      af[mi][1] = *(const bf16x8*)((const char*)ldsA + row * 128 + ((64 | kb0) ^ swz));
    }
    {
      bf16x8 bv[8];
#pragma unroll
      for (int ni = 0; ni < 8; ++ni) {
        const int row = (wc << 7) + (ni << 4) + l15;
        bv[ni] = *(const bf16x8*)((const char*)ldsB + row * 128 +
                                  (kb0 ^ ((row & 7) << 4)));
      }
#pragma unroll
      for (int mi = 0; mi < 4; ++mi)
#pragma unroll
        for (int ni = 0; ni < 8; ++ni)
          acc[mi][ni] = __builtin_amdgcn_mfma_f32_16x16x32_bf16(
              af[mi][0], bv[ni], acc[mi][ni], 0, 0, 0);
    }
    {
      bf16x8 bv[8];
#pragma unroll
      for (int ni = 0; ni < 8; ++ni) {
        const int row = (wc << 7) + (ni << 4) + l15;
        bv[ni] = *(const bf16x8*)((const char*)ldsB + row * 128 +
                                  ((64 | kb0) ^ ((row & 7) << 4)));
      }
#pragma unroll
      for (int mi = 0; mi < 4; ++mi)
#pragma unroll
        for (int ni = 0; ni < 8; ++ni)
          acc[mi][ni] = __builtin_amdgcn_mfma_f32_16x16x32_bf16(
              af[mi][1], bv[ni], acc[mi][ni], 0, 0, 0);
    }
    __syncthreads();   // all reads done before next stage overwrites
  }

  // Epilogue: scale by rsig; z=0 -> f32 out, z=1 -> bf16 partial.
  // C/D: col(=p)=lane&15, row(=o)=(lane>>4)*4+r
#pragma unroll
  for (int mi = 0; mi < 4; ++mi) {
    const int o = bo0 + (wr << 6) + (mi << 4) + ((lane >> 4) << 2);
    const f32x4 rs = *(const f32x4*)(rsig + (bimg << 9) + o);
#pragma unroll
    for (int ni = 0; ni < 8; ++ni) {
      const int p = bp0 + (wc << 7) + (ni << 4) + l15;
      const int prem = p & 1023;
      if (z == 0) {
#pragma unroll
        for (int r = 0; r < 4; ++r)
          out[((size_t)(bimg << 9) + o + r) * 1024 + prem] =
              acc[mi][ni][r] * rs[r];
      } else {
#pragma unroll
        for (int r = 0; r < 4; ++r)
          p1[((size_t)(bimg << 9) + o + r) * 1024 + prem] =
              __float2bfloat16(acc[mi][ni][r] * rs[r]);
      }
    }
  }
}

// ---- kernel 5: merge out += p1 (8 elems/thread) ----
__global__ __launch_bounds__(256) void merge_kernel(
    float* __restrict__ out, const __hip_bfloat16* __restrict__ p1) {
  const int i = blockIdx.x * 256 + threadIdx.x;   // one per 8 elements
  f32x4* o4 = (f32x4*)out + 2 * (size_t)i;
  f32x4 a = o4[0], b = o4[1];
  const bf16x8 pv = ((const bf16x8*)p1)[i];
#pragma unroll
  for (int j = 0; j < 4; ++j) {
    a[j] += __uint_as_float(((unsigned)(unsigned short)pv[j]) << 16);
    b[j] += __uint_as_float(((unsigned)(unsigned short)pv[4 + j]) << 16);
  }
  o4[0] = a;
  o4[1] = b;
}

extern "C" void kernel_launch(void* const* d_in, const int* in_sizes, int n_in,
                              void* d_out, int out_size, void* d_ws,
                              size_t ws_size, hipStream_t stream) {
  const float* x = (const float*)d_in[0];   // [16,512,32,32]
  const float* s = (const float*)d_in[1];   // [16,512]
  const float* w = (const float*)d_in[2];   // [512,512,3,3]
  float* out = (float*)d_out;               // [16,512,32,32] f32

  char* ws = (char*)d_ws;
  const size_t xpad_bytes = (size_t)NB * 34 * 34 * 512 * 2;  // 18,939,904
  const size_t wB_bytes = (size_t)COUT * KTOT * 2;           //  4,718,592
  const size_t wsq_bytes = (size_t)COUT * CIN * 4;           //  1,048,576
  const size_t rsig_bytes = (size_t)NB * COUT * 4;           //     32,768
  __hip_bfloat16* xpad = (__hip_bfloat16*)ws;
  __hip_bfloat16* wB = (__hip_bfloat16*)(ws + xpad_bytes);
  float* wsq = (float*)(ws + xpad_bytes + wB_bytes);
  float* rsig = (float*)(ws + xpad_bytes + wB_bytes + wsq_bytes);
  __hip_bfloat16* p1 =
      (__hip_bfloat16*)(ws + xpad_bytes + wB_bytes + wsq_bytes + rsig_bytes);
  // total ws use: ~41.5 MB (p1 partial = 16.8 MB)

  hipMemsetAsync(xpad, 0, xpad_bytes, stream);  // zero halo (capturable)
  pack_w_kernel<<<(COUT * CIN) / 256, 256, 0, stream>>>(w, wB, wsq);
  modulate_kernel<<<NB * 32, 256, 0, stream>>>(x, s, xpad);
  calc_rsig_kernel<<<(NB * COUT) / 4, 256, 0, stream>>>(s, wsq, rsig);
  conv_gemm_kernel<<<dim3(NPIX / 256, COUT / 128, 2), 256, 0, stream>>>(
      wB, xpad, rsig, out, p1);
  merge_kernel<<<(NPIX * COUT / 8) / 256, 256, 0, stream>>>(out, p1);
}